// Round 2
// baseline (2302.129 us; speedup 1.0000x reference)
//
#include <hip/hip_runtime.h>

// Problem constants (match reference setup_inputs)
#define BB   4
#define LL   2048
#define CC   1024
#define CHB  256               // channels per block (= blockDim.x)
#define CG   (CC / CHB)        // 4 channel-groups per batch
#define NROWS (BB * CG)        // 16 independent scan rows
#define SEGLEN 16              // L-steps per block
#define NSEG (LL / SEGLEN)     // 128 segments per row
#define NBLK (NROWS * NSEG)    // 2048 blocks

// ws layout (floats): [0..15] ticket (int at [0]); [16..16+NBLK) flags (ints);
// agg at 4096: [NBLK][CHB][16]; incl after: [NBLK][CHB][8].  Total ~48 MiB.

typedef float v4f __attribute__((ext_vector_type(4)));

struct Cplx { float r, i; };

__device__ __forceinline__ Cplx cmul(Cplx a, Cplx b) {
    Cplx o;
    o.r = fmaf(a.r, b.r, -a.i * b.i);
    o.i = fmaf(a.r, b.i,  a.i * b.r);
    return o;
}
__device__ __forceinline__ Cplx cfma(Cplx a, Cplx b, Cplx acc) {
    acc.r = fmaf(a.r, b.r, fmaf(-a.i, b.i, acc.r));
    acc.i = fmaf(a.r, b.i, fmaf( a.i, b.r, acc.i));
    return acc;
}

__device__ __forceinline__ void load_mat(const float* __restrict__ p, Cplx m[4]) {
    const v4f* p4 = (const v4f*)p;
    v4f v0 = p4[0], v1 = p4[1];
    m[0].r = v0.x; m[0].i = v0.y; m[1].r = v0.z; m[1].i = v0.w;
    m[2].r = v1.x; m[2].i = v1.y; m[3].r = v1.z; m[3].i = v1.w;
}
__device__ __forceinline__ void load_mat_nt(const float* __restrict__ p, Cplx m[4]) {
    const v4f* p4 = (const v4f*)p;
    v4f v0 = __builtin_nontemporal_load(p4);
    v4f v1 = __builtin_nontemporal_load(p4 + 1);
    m[0].r = v0.x; m[0].i = v0.y; m[1].r = v0.z; m[1].i = v0.w;
    m[2].r = v1.x; m[2].i = v1.y; m[3].r = v1.z; m[3].i = v1.w;
}
__device__ __forceinline__ void store_mat(float* __restrict__ p, const Cplx m[4]) {
    v4f* p4 = (v4f*)p;
    p4[0] = (v4f){m[0].r, m[0].i, m[1].r, m[1].i};
    p4[1] = (v4f){m[2].r, m[2].i, m[3].r, m[3].i};
}
__device__ __forceinline__ void store_mat_nt(float* __restrict__ p, const Cplx m[4]) {
    v4f* p4 = (v4f*)p;
    v4f v0 = {m[0].r, m[0].i, m[1].r, m[1].i};
    v4f v1 = {m[2].r, m[2].i, m[3].r, m[3].i};
    __builtin_nontemporal_store(v0, p4);
    __builtin_nontemporal_store(v1, p4 + 1);
}

// out = a @ m (2x2 complex)
__device__ __forceinline__ void matmul(const Cplx a[4], const Cplx m[4], Cplx out[4]) {
    #pragma unroll
    for (int ik = 0; ik < 4; ++ik) {
        int i = ik >> 1, k = ik & 1;
        Cplx t = cmul(a[i * 2 + 0], m[0 * 2 + k]);
        out[ik] = cfma(a[i * 2 + 1], m[1 * 2 + k], t);
    }
}
// out = a @ m + x
__device__ __forceinline__ void matmul_add(const Cplx a[4], const Cplx m[4],
                                           const Cplx x[4], Cplx out[4]) {
    #pragma unroll
    for (int ik = 0; ik < 4; ++ik) {
        int i = ik >> 1, k = ik & 1;
        Cplx t = cfma(a[i * 2 + 0], m[0 * 2 + k], x[ik]);
        out[ik] = cfma(a[i * 2 + 1], m[1 * 2 + k], t);
    }
}

__global__ void pscan_init(int* __restrict__ w) {
    int i = blockIdx.x * blockDim.x + threadIdx.x;
    if (i < 4096) w[i] = 0;   // ticket + flags
}

__global__ __launch_bounds__(256) void pscan_lookback(const float* __restrict__ A,
                                                      const float* __restrict__ X,
                                                      float* __restrict__ out,
                                                      float* __restrict__ ws) {
    __shared__ int sh_wid;
    __shared__ int sh_f;
    int*   ticket = (int*)ws;
    int*   flags  = (int*)ws + 16;
    float* agg    = ws + 4096;
    float* incl   = ws + 4096 + (long)NBLK * CHB * 16;

    // Ticket-ordered work assignment: seg-major so every lookback target has a
    // strictly lower ticket => held by an already-running block => deadlock-free
    // regardless of dispatch order (G16-safe).
    if (threadIdx.x == 0) sh_wid = atomicAdd(ticket, 1);
    __syncthreads();
    const int wid = sh_wid;
    const int seg = wid / NROWS;
    const int row = wid % NROWS;
    const int b   = row / CG;
    const int cg  = row % CG;
    const int c   = cg * CHB + threadIdx.x;

    const long step = (long)CC * 8;
    long base = (((long)b * LL + (long)seg * SEGLEN) * CC + c) * 8;

    // ---- Phase A: local segment aggregate (Ac, Xc) ----
    Cplx Ac[4], Xc[4];
    load_mat(A + base, Ac);
    load_mat(X + base, Xc);
    {
        long p = base + step;
        #pragma unroll 4
        for (int t = 1; t < SEGLEN; ++t, p += step) {
            Cplx a[4], x[4], nA[4], nX[4];
            load_mat(A + p, a);
            load_mat(X + p, x);
            matmul(a, Ac, nA);           // Ac = a @ Ac
            matmul_add(a, Xc, x, nX);    // Xc = a @ Xc + x
            #pragma unroll
            for (int j = 0; j < 4; ++j) { Ac[j] = nA[j]; Xc[j] = nX[j]; }
        }
    }

    const long slot   = ((long)row * NSEG + seg) * CHB + threadIdx.x;
    const int  myFlag = row * NSEG + seg;

    Cplx carry[4];

    if (seg == 0) {
        #pragma unroll
        for (int j = 0; j < 4; ++j) { carry[j].r = 0.f; carry[j].i = 0.f; }
        store_mat(incl + slot * 8, Xc);        // inclusive Y at end of seg 0
        __threadfence();
        __syncthreads();
        if (threadIdx.x == 0)
            __hip_atomic_store(&flags[myFlag], 2, __ATOMIC_RELEASE, __HIP_MEMORY_SCOPE_AGENT);
    } else {
        // Publish aggregate early so successors can pre-combine.
        float* ag = agg + slot * 16;
        store_mat(ag,     Ac);
        store_mat(ag + 8, Xc);
        __threadfence();
        __syncthreads();
        if (threadIdx.x == 0)
            __hip_atomic_store(&flags[myFlag], 1, __ATOMIC_RELEASE, __HIP_MEMORY_SCOPE_AGENT);

        // Lookback: combine aggregates rightward-in until an inclusive is found.
        Cplx AT[4], XT[4];                     // transform of (p, seg-1]
        AT[0] = {1.f, 0.f}; AT[1] = {0.f, 0.f};
        AT[2] = {0.f, 0.f}; AT[3] = {1.f, 0.f};
        #pragma unroll
        for (int j = 0; j < 4; ++j) { XT[j].r = 0.f; XT[j].i = 0.f; }

        int p = seg - 1;
        for (;;) {
            if (threadIdx.x == 0) {
                int f;
                while ((f = __hip_atomic_load(&flags[row * NSEG + p],
                                              __ATOMIC_ACQUIRE,
                                              __HIP_MEMORY_SCOPE_AGENT)) < 1)
                    __builtin_amdgcn_s_sleep(1);
                sh_f = f;
            }
            __syncthreads();
            const int f = sh_f;
            const long ps = ((long)row * NSEG + p) * CHB + threadIdx.x;
            if (f == 2) {
                Cplx Yp[4];
                load_mat(incl + ps * 8, Yp);
                matmul_add(AT, Yp, XT, carry); // carry = AT @ Y_p + XT
                break;
            } else {
                Cplx Ap[4], Xp[4], nA[4], nX[4];
                const float* ag2 = agg + ps * 16;
                load_mat(ag2,     Ap);
                load_mat(ag2 + 8, Xp);
                matmul(AT, Ap, nA);            // AT = AT @ Ap
                matmul_add(AT, Xp, XT, nX);    // XT = AT @ Xp + XT
                #pragma unroll
                for (int j = 0; j < 4; ++j) { AT[j] = nA[j]; XT[j] = nX[j]; }
                --p;
            }
            __syncthreads();   // protect sh_f before next-iteration overwrite
        }

        // Publish our inclusive BEFORE phase B to unblock successors ASAP.
        Cplx Yi[4];
        matmul_add(Ac, carry, Xc, Yi);
        store_mat(incl + slot * 8, Yi);
        __threadfence();
        __syncthreads();
        if (threadIdx.x == 0)
            __hip_atomic_store(&flags[myFlag], 2, __ATOMIC_RELEASE, __HIP_MEMORY_SCOPE_AGENT);
    }

    // ---- Phase B: re-scan segment (tile hot in L2/L3), write outputs ----
    Cplx Y[4];
    #pragma unroll
    for (int j = 0; j < 4; ++j) Y[j] = carry[j];

    #pragma unroll 2
    for (int t = 0; t < SEGLEN; ++t, base += step) {
        Cplx a[4], x[4], nY[4];
        load_mat_nt(A + base, a);
        load_mat_nt(X + base, x);
        matmul_add(a, Y, x, nY);               // Y = a @ Y + x
        #pragma unroll
        for (int j = 0; j < 4; ++j) Y[j] = nY[j];
        store_mat_nt(out + base, Y);           // NT: don't evict live tiles
    }
}

extern "C" void kernel_launch(void* const* d_in, const int* in_sizes, int n_in,
                              void* d_out, int out_size, void* d_ws, size_t ws_size,
                              hipStream_t stream) {
    const float* A = (const float*)d_in[0];
    const float* X = (const float*)d_in[1];
    float* out = (float*)d_out;
    float* ws  = (float*)d_ws;   // needs ~48.1 MiB

    pscan_init<<<16, 256, 0, stream>>>((int*)ws);
    pscan_lookback<<<NBLK, 256, 0, stream>>>(A, X, out, ws);
}